// Round 2
// baseline (1636.460 us; speedup 1.0000x reference)
//
#include <hip/hip_runtime.h>

#define TMAX 128

__device__ __forceinline__ float silu_f(float x) {
    return x / (1.f + __expf(-x));
}
__device__ __forceinline__ float softplus_f(float x) {
    return (x > 20.f) ? x : log1pf(__expf(x));
}

// ---------------- transpose in: x (B,C,H,W) -> xh (B,H,W,C) ----------------
__global__ __launch_bounds__(256) void k_tr_in(const float* __restrict__ x, float* __restrict__ xh) {
    __shared__ float tile[128 * 65];
    int h = blockIdx.x, b = blockIdx.y;
    const float* ip = x + (size_t)b * 64 * 16384 + (size_t)h * 128;
    for (int i = threadIdx.x; i < 64 * 128; i += 256) {
        int c = i >> 7, w = i & 127;
        tile[w * 65 + c] = ip[(size_t)c * 16384 + w];
    }
    __syncthreads();
    float* op = xh + ((size_t)(b * 128 + h)) * 128 * 64;
    for (int i = threadIdx.x; i < 128 * 64; i += 256) {
        int w = i >> 6, c = i & 63;
        op[i] = tile[w * 65 + c];
    }
}

// ---------------- transpose out: res (B,H,W,C) -> out (B,C,W,H) ----------------
__global__ __launch_bounds__(256) void k_tr_out(const float* __restrict__ res, float* __restrict__ out) {
    __shared__ float tile[64 * 129];
    int w = blockIdx.x, b = blockIdx.y;
    const float* ip = res + (size_t)b * 16384 * 64 + (size_t)w * 64;
    for (int i = threadIdx.x; i < 128 * 64; i += 256) {
        int h = i >> 6, c = i & 63;
        tile[c * 129 + h] = ip[(size_t)h * 128 * 64 + c];
    }
    __syncthreads();
    float* op = out + (size_t)b * 64 * 16384 + (size_t)w * 128;
    for (int i = threadIdx.x; i < 64 * 128; i += 256) {
        int c = i >> 7, hh = i & 127;
        op[(size_t)c * 16384 + hh] = tile[c * 129 + hh];
    }
}

// ---------------- downsample: xh_l (B,2Ho,2Wo,64) -> xh_{l+1} (B,Ho,Wo,64) ----------------
__global__ __launch_bounds__(256) void k_down(const float* __restrict__ in, float* __restrict__ out,
                                              const float* __restrict__ dwp, int Ho, int Wo, int ntot) {
    __shared__ float dw[16384]; // [ (c*4+pq) * 64 + o ]
    for (int i = threadIdx.x; i < 16384; i += 256) {
        int o = i & 63, cpq = i >> 6;
        dw[cpq * 64 + o] = dwp[o * 256 + cpq];
    }
    __syncthreads();
    int gid = blockIdx.x * 256 + threadIdx.x;
    if (gid >= ntot) return;
    int og = gid & 3, pix = gid >> 2;
    int j = pix % Wo, i2 = (pix / Wo) % Ho, b = pix / (Wo * Ho);
    const float* ip = in + (((size_t)b * (2 * Ho) + 2 * i2) * (size_t)(2 * Wo) + 2 * j) * 64;
    float acc[16];
#pragma unroll
    for (int m = 0; m < 16; ++m) acc[m] = 0.f;
    for (int p = 0; p < 2; ++p) {
        for (int q = 0; q < 2; ++q) {
            const float* xp = ip + ((size_t)p * (2 * Wo) + q) * 64;
            for (int c = 0; c < 64; ++c) {
                float xv = xp[c];
                const float* wrow = &dw[(c * 4 + p * 2 + q) * 64 + og * 16];
#pragma unroll
                for (int m = 0; m < 16; ++m) acc[m] = fmaf(xv, wrow[m], acc[m]);
            }
        }
    }
    float* op = out + (size_t)pix * 64 + og * 16;
#pragma unroll
    for (int m = 0; m < 4; ++m) {
        float4 v = make_float4(acc[m * 4], acc[m * 4 + 1], acc[m * 4 + 2], acc[m * 4 + 3]);
        *(float4*)(op + m * 4) = v;
    }
}

// ---------------- upsample-accumulate: out_l += coef * up(out_{l+1}) ----------------
__global__ __launch_bounds__(256) void k_up(const float* __restrict__ src, float* __restrict__ dst,
                                            const float* __restrict__ uwp, int H, int W, float coef, int ntot) {
    __shared__ float uw[16384]; // [ (c*4+pq) * 64 + o ]
    for (int i = threadIdx.x; i < 16384; i += 256) {
        int o = i & 63, cpq = i >> 6;
        int c = cpq >> 2, pq = cpq & 3;
        uw[cpq * 64 + o] = uwp[c * 256 + o * 4 + pq];
    }
    __syncthreads();
    int gid = blockIdx.x * 256 + threadIdx.x;
    if (gid >= ntot) return;
    int og = gid & 3, pix = gid >> 2;
    int x = pix % W, y = (pix / W) % H, b = pix / (W * H);
    int Hs = H >> 1, Ws = W >> 1;
    int pq = (y & 1) * 2 + (x & 1);
    const float* sp = src + (((size_t)b * Hs + (y >> 1)) * (size_t)Ws + (x >> 1)) * 64;
    float acc[16];
#pragma unroll
    for (int m = 0; m < 16; ++m) acc[m] = 0.f;
    for (int c = 0; c < 64; ++c) {
        float xv = sp[c];
        const float* wrow = &uw[(c * 4 + pq) * 64 + og * 16];
#pragma unroll
        for (int m = 0; m < 16; ++m) acc[m] = fmaf(xv, wrow[m], acc[m]);
    }
    float* op = dst + (size_t)pix * 64 + og * 16;
#pragma unroll
    for (int m = 0; m < 4; ++m) {
        float4 cur = *(float4*)(op + m * 4);
        cur.x += coef * acc[m * 4];
        cur.y += coef * acc[m * 4 + 1];
        cur.z += coef * acc[m * 4 + 2];
        cur.w += coef * acc[m * 4 + 3];
        *(float4*)(op + m * 4) = cur;
    }
}

// ---------------- LayerNorm over C=64, thread per token ----------------
__global__ __launch_bounds__(256) void k_ln(const float* __restrict__ in, float* __restrict__ out,
                                            const float* __restrict__ w, const float* __restrict__ bb, int ntok) {
    int t = blockIdx.x * 256 + threadIdx.x;
    if (t >= ntok) return;
    const float4* p = (const float4*)(in + (size_t)t * 64);
    float4 v[16];
    float s = 0.f;
#pragma unroll
    for (int i = 0; i < 16; ++i) {
        v[i] = p[i];
        s += v[i].x + v[i].y + v[i].z + v[i].w;
    }
    float m = s * (1.f / 64.f);
    float q = 0.f;
#pragma unroll
    for (int i = 0; i < 16; ++i) {
        float a = v[i].x - m, b2 = v[i].y - m, c = v[i].z - m, d = v[i].w - m;
        q += a * a + b2 * b2 + c * c + d * d;
    }
    float r = rsqrtf(q * (1.f / 64.f) + 1e-5f);
    float4* o = (float4*)(out + (size_t)t * 64);
    const float4* w4 = (const float4*)w;
    const float4* b4 = (const float4*)bb;
#pragma unroll
    for (int i = 0; i < 16; ++i) {
        float4 ww = w4[i], bbv = b4[i];
        float4 ov;
        ov.x = (v[i].x - m) * r * ww.x + bbv.x;
        ov.y = (v[i].y - m) * r * ww.y + bbv.y;
        ov.z = (v[i].z - m) * r * ww.z + bbv.z;
        ov.w = (v[i].w - m) * r * ww.w + bbv.w;
        o[i] = ov;
    }
}

// ---------------- LN2 + proj (64x64) ----------------
__global__ __launch_bounds__(256) void k_post(const float* __restrict__ ym, float* __restrict__ outl,
                                              const float* __restrict__ lnw, const float* __restrict__ lnb,
                                              const float* __restrict__ proj_w, const float* __restrict__ proj_b,
                                              int ntok) {
    __shared__ float pw[4096];
    __shared__ float pb[64];
    __shared__ float lw[64], lb[64];
    for (int i = threadIdx.x; i < 4096; i += 256) pw[i] = proj_w[i];
    if (threadIdx.x < 64) {
        pb[threadIdx.x] = proj_b[threadIdx.x];
        lw[threadIdx.x] = lnw[threadIdx.x];
        lb[threadIdx.x] = lnb[threadIdx.x];
    }
    __syncthreads();
    int t = blockIdx.x * 256 + threadIdx.x;
    if (t >= ntok) return;
    const float4* p = (const float4*)(ym + (size_t)t * 64);
    float4 v[16];
    float s = 0.f;
#pragma unroll
    for (int i = 0; i < 16; ++i) {
        v[i] = p[i];
        s += v[i].x + v[i].y + v[i].z + v[i].w;
    }
    float m = s * (1.f / 64.f);
    float q = 0.f;
#pragma unroll
    for (int i = 0; i < 16; ++i) {
        float a = v[i].x - m, b2 = v[i].y - m, c = v[i].z - m, d = v[i].w - m;
        q += a * a + b2 * b2 + c * c + d * d;
    }
    float r = rsqrtf(q * (1.f / 64.f) + 1e-5f);
    float* op = outl + (size_t)t * 64;
    for (int half = 0; half < 2; ++half) {
        float acc[32];
#pragma unroll
        for (int o = 0; o < 32; ++o) acc[o] = pb[half * 32 + o];
#pragma unroll
        for (int i = 0; i < 16; ++i) {
            float vals[4] = {v[i].x, v[i].y, v[i].z, v[i].w};
#pragma unroll
            for (int k = 0; k < 4; ++k) {
                int c = i * 4 + k;
                float vn = (vals[k] - m) * r * lw[c] + lb[c];
                const float* wrow = &pw[c * 64 + half * 32];
#pragma unroll
                for (int o = 0; o < 32; ++o) acc[o] = fmaf(vn, wrow[o], acc[o]);
            }
        }
#pragma unroll
        for (int mq = 0; mq < 8; ++mq) {
            float4 ov = make_float4(acc[mq * 4], acc[mq * 4 + 1], acc[mq * 4 + 2], acc[mq * 4 + 3]);
            *(float4*)(op + half * 32 + mq * 4) = ov;
        }
    }
}

// ---------------- fused mamba chunk kernel (phase A: P/Hloc, phase C: y + epilogue) ----------------
template <int PHASE> // 0 = A, 1 = C
__global__ __launch_bounds__(256, 2) void k_scan(const float* __restrict__ xn,
                                                 float* __restrict__ Pbuf, float* __restrict__ Hbuf,
                                                 const float* __restrict__ hinbuf, float* __restrict__ ym,
                                                 const float* __restrict__ in_proj_w, const float* __restrict__ conv_w,
                                                 const float* __restrict__ conv_b, const float* __restrict__ x_proj_w,
                                                 const float* __restrict__ dt_w, const float* __restrict__ dt_b,
                                                 const float* __restrict__ A_log, const float* __restrict__ Dvec,
                                                 const float* __restrict__ out_proj_w, const float* __restrict__ skip_scale,
                                                 int n, int nch) {
    __shared__ float Wm[16][32];
    __shared__ float Wz[16][32];
    __shared__ float cw[32][4];
    __shared__ float cb[32];
    __shared__ float Wxp[32][33];
    __shared__ float dtw[32], dtb[32];
    __shared__ float Ash[32][16];
    __shared__ float Dsh[32];
    __shared__ float Wout[32][16];
    __shared__ float xmpre_y[(TMAX + 3) * 32]; // stage1 pre-conv, later aliased as y[t][d]
    __shared__ float dt_s[TMAX][32];
    __shared__ float xm_s[TMAX][32];
    __shared__ float Bs[TMAX][16];
    __shared__ float Cs[TMAX][16];

    const int tid = threadIdx.x;
    const int chunk = blockIdx.x;
    const int seq = blockIdx.y;
    const int g = seq >> 3, b = seq & 7;
    const int t0 = chunk * TMAX;
    const int Tc = (n - t0 < TMAX) ? (n - t0) : TMAX;

    // stage weights to LDS
    for (int i = tid; i < 16 * 32; i += 256) {
        int k = i >> 5, d = i & 31;
        Wm[k][d] = in_proj_w[k * 64 + d];
        Wz[k][d] = in_proj_w[k * 64 + 32 + d];
    }
    for (int i = tid; i < 32 * 4; i += 256) cw[i >> 2][i & 3] = conv_w[i];
    if (tid < 32) {
        cb[tid] = conv_b[tid];
        dtw[tid] = dt_w[tid];
        dtb[tid] = dt_b[tid];
        Dsh[tid] = Dvec[tid];
    }
    for (int i = tid; i < 32 * 33; i += 256) Wxp[i / 33][i % 33] = x_proj_w[i];
    for (int i = tid; i < 32 * 16; i += 256) {
        Ash[i >> 4][i & 15] = -__expf(A_log[i]);
        Wout[i >> 4][i & 15] = out_proj_w[i];
    }
    __syncthreads();

    const float* xbase = xn + (size_t)b * n * 64 + g * 16;

    // stage 1: in_proj (xm half) for tokens [t0-3, t0+Tc)
    if (tid < Tc + 3) {
        int t = t0 + tid - 3;
        float* dst = &xmpre_y[tid * 32];
        if (t < 0) {
#pragma unroll
            for (int d = 0; d < 32; ++d) dst[d] = 0.f;
        } else {
            const float4* xp = (const float4*)(xbase + (size_t)t * 64);
            float4 x0 = xp[0], x1 = xp[1], x2 = xp[2], x3 = xp[3];
            float xc[16] = {x0.x, x0.y, x0.z, x0.w, x1.x, x1.y, x1.z, x1.w,
                            x2.x, x2.y, x2.z, x2.w, x3.x, x3.y, x3.z, x3.w};
#pragma unroll
            for (int d = 0; d < 32; ++d) {
                float a = 0.f;
#pragma unroll
                for (int k = 0; k < 16; ++k) a = fmaf(xc[k], Wm[k][d], a);
                dst[d] = a;
            }
        }
    }
    __syncthreads();

    // stage 2: conv + silu + x_proj + dt
    if (tid < Tc) {
        float xmv[32];
#pragma unroll
        for (int d = 0; d < 32; ++d) {
            float a = cb[d];
#pragma unroll
            for (int k = 0; k < 4; ++k) a = fmaf(xmpre_y[(tid + k) * 32 + d], cw[d][k], a);
            float sv = silu_f(a);
            xmv[d] = sv;
            xm_s[tid][d] = sv;
        }
        float dtr = 0.f;
#pragma unroll
        for (int d = 0; d < 32; ++d) dtr = fmaf(xmv[d], Wxp[d][0], dtr);
#pragma unroll
        for (int s = 0; s < 16; ++s) {
            float bv = 0.f;
#pragma unroll
            for (int d = 0; d < 32; ++d) bv = fmaf(xmv[d], Wxp[d][1 + s], bv);
            Bs[tid][s] = bv;
            if (PHASE == 1) {
                float cv = 0.f;
#pragma unroll
                for (int d = 0; d < 32; ++d) cv = fmaf(xmv[d], Wxp[d][17 + s], cv);
                Cs[tid][s] = cv;
            }
        }
#pragma unroll
        for (int d = 0; d < 32; ++d) dt_s[tid][d] = softplus_f(fmaf(dtr, dtw[d], dtb[d]));
    }
    __syncthreads();

    // scan: thread owns (d, s0) and (d, s0+1)
    const int d = tid >> 3;
    const int s0 = (tid & 7) * 2;
    const float a0 = Ash[d][s0], a1 = Ash[d][s0 + 1];
    float h0, h1;
    const size_t cbi = ((size_t)seq * nch + chunk) * 512 + tid * 2;
    if (PHASE == 1) {
        float2 hi = *(const float2*)&hinbuf[cbi];
        h0 = hi.x;
        h1 = hi.y;
    } else {
        h0 = 0.f;
        h1 = 0.f;
    }
    float sdt = 0.f;
#pragma unroll 2
    for (int t = 0; t < Tc; ++t) {
        float dtv = dt_s[t][d];
        float u = dtv * xm_s[t][d];
        float2 bb2 = *(const float2*)&Bs[t][s0];
        float e0 = __expf(dtv * a0), e1 = __expf(dtv * a1);
        h0 = fmaf(e0, h0, u * bb2.x);
        h1 = fmaf(e1, h1, u * bb2.y);
        if (PHASE == 0) {
            sdt += dtv;
        } else {
            float2 cc = *(const float2*)&Cs[t][s0];
            float pp = fmaf(h0, cc.x, h1 * cc.y);
            pp += __shfl_xor(pp, 1);
            pp += __shfl_xor(pp, 2);
            pp += __shfl_xor(pp, 4);
            if ((tid & 7) == 0) xmpre_y[t * 32 + d] = pp;
        }
    }
    if (PHASE == 0) {
        float2 pv;
        pv.x = __expf(a0 * sdt);
        pv.y = __expf(a1 * sdt);
        *(float2*)&Pbuf[cbi] = pv;
        float2 hv;
        hv.x = h0;
        hv.y = h1;
        *(float2*)&Hbuf[cbi] = hv;
    } else {
        __syncthreads();
        // epilogue: gate + out_proj + skip, write regrouped ym
        if (tid < Tc) {
            int t = t0 + tid;
            const float4* xp = (const float4*)(xbase + (size_t)t * 64);
            float4 x0 = xp[0], x1 = xp[1], x2 = xp[2], x3 = xp[3];
            float xc[16] = {x0.x, x0.y, x0.z, x0.w, x1.x, x1.y, x1.z, x1.w,
                            x2.x, x2.y, x2.z, x2.w, x3.x, x3.y, x3.z, x3.w};
            float yv[32];
#pragma unroll
            for (int dd = 0; dd < 32; ++dd) {
                float zz = 0.f;
#pragma unroll
                for (int k = 0; k < 16; ++k) zz = fmaf(xc[k], Wz[k][dd], zz);
                float yb = xmpre_y[tid * 32 + dd] + xm_s[tid][dd] * Dsh[dd];
                yv[dd] = yb * silu_f(zz);
            }
            float ss = skip_scale[0];
            float* ymtok = ym + ((size_t)b * n + t) * 64 + g * 16;
#pragma unroll
            for (int jq = 0; jq < 4; ++jq) {
                float4 ov;
                float o0 = 0.f, o1 = 0.f, o2 = 0.f, o3 = 0.f;
#pragma unroll
                for (int dd = 0; dd < 32; ++dd) {
                    o0 = fmaf(yv[dd], Wout[dd][jq * 4 + 0], o0);
                    o1 = fmaf(yv[dd], Wout[dd][jq * 4 + 1], o1);
                    o2 = fmaf(yv[dd], Wout[dd][jq * 4 + 2], o2);
                    o3 = fmaf(yv[dd], Wout[dd][jq * 4 + 3], o3);
                }
                ov.x = o0 + ss * xc[jq * 4 + 0];
                ov.y = o1 + ss * xc[jq * 4 + 1];
                ov.z = o2 + ss * xc[jq * 4 + 2];
                ov.w = o3 + ss * xc[jq * 4 + 3];
                *(float4*)(ymtok + jq * 4) = ov;
            }
        }
    }
}

// ---------------- phase B: sequential combine across chunks ----------------
__global__ __launch_bounds__(256) void k_scanB(const float* __restrict__ P, const float* __restrict__ Hl,
                                               float* __restrict__ hin, int nch) {
    int idx = blockIdx.x * 256 + threadIdx.x; // 16384 threads
    int seq = idx >> 9, ds = idx & 511;
    size_t base = (size_t)seq * nch * 512 + ds;
    float h = 0.f;
    for (int k = 0; k < nch; ++k) {
        hin[base + (size_t)k * 512] = h;
        h = fmaf(P[base + (size_t)k * 512], h, Hl[base + (size_t)k * 512]);
    }
}

// ---------------- launcher ----------------
extern "C" void kernel_launch(void* const* d_in, const int* in_sizes, int n_in,
                              void* d_out, int out_size, void* d_ws, size_t ws_size,
                              hipStream_t stream) {
    (void)in_sizes; (void)n_in; (void)out_size; (void)ws_size;
    const float* x          = (const float*)d_in[0];
    const float* ln_w       = (const float*)d_in[1];
    const float* ln_b       = (const float*)d_in[2];
    const float* skip_scale = (const float*)d_in[3];
    const float* proj_w     = (const float*)d_in[4];
    const float* proj_b     = (const float*)d_in[5];
    const float* in_proj_w  = (const float*)d_in[6];
    const float* conv_w     = (const float*)d_in[7];
    const float* conv_b     = (const float*)d_in[8];
    const float* x_proj_w   = (const float*)d_in[9];
    const float* dt_proj_w  = (const float*)d_in[10];
    const float* dt_proj_b  = (const float*)d_in[11];
    const float* A_log      = (const float*)d_in[12];
    const float* Dv         = (const float*)d_in[13];
    const float* out_proj_w = (const float*)d_in[14];
    const float* down_w     = (const float*)d_in[15];
    const float* up_w       = (const float*)d_in[16];
    float* out = (float*)d_out;
    float* ws = (float*)d_ws;

    // sizes per level (floats): B*n*64
    static const int nl[5] = {16384, 4096, 1024, 256, 64};
    static const size_t off_xh[5] = {0, 8388608, 10485760, 11010048, 11141120};
    static const size_t off_out[5] = {11173888, 19562496, 21659648, 22183936, 22315008};
    const size_t off_xn = 22347776;
    const size_t off_P = 30736384;
    const size_t off_H = 32833536;
    const size_t off_hin = 34930688;
    const size_t off_ym = 0; // aliases xh0 (dead after LN level 0 and downs)

    // 1. transpose input
    k_tr_in<<<dim3(128, 8), dim3(256), 0, stream>>>(x, ws + off_xh[0]);

    // 2. downsample chain (before xh0 is reused as ym)
    for (int l = 0; l < 4; ++l) {
        int Ho = 128 >> (l + 1);
        int ntot = 8 * Ho * Ho * 4;
        k_down<<<dim3((ntot + 255) / 256), dim3(256), 0, stream>>>(ws + off_xh[l], ws + off_xh[l + 1],
                                                                   down_w, Ho, Ho, ntot);
    }

    // 3. per-level mamba pipeline
    for (int l = 0; l < 5; ++l) {
        int n = nl[l];
        int ntok = 8 * n;
        int nch = (n + TMAX - 1) / TMAX;
        k_ln<<<dim3((ntok + 255) / 256), dim3(256), 0, stream>>>(ws + off_xh[l], ws + off_xn, ln_w, ln_b, ntok);
        k_scan<0><<<dim3(nch, 32), dim3(256), 0, stream>>>(ws + off_xn, ws + off_P, ws + off_H, nullptr, nullptr,
                                                           in_proj_w, conv_w, conv_b, x_proj_w, dt_proj_w, dt_proj_b,
                                                           A_log, Dv, out_proj_w, skip_scale, n, nch);
        k_scanB<<<dim3(64), dim3(256), 0, stream>>>(ws + off_P, ws + off_H, ws + off_hin, nch);
        k_scan<1><<<dim3(nch, 32), dim3(256), 0, stream>>>(ws + off_xn, nullptr, nullptr, ws + off_hin, ws + off_ym,
                                                           in_proj_w, conv_w, conv_b, x_proj_w, dt_proj_w, dt_proj_b,
                                                           A_log, Dv, out_proj_w, skip_scale, n, nch);
        k_post<<<dim3((ntok + 255) / 256), dim3(256), 0, stream>>>(ws + off_ym, ws + off_out[l], ln_w, ln_b,
                                                                   proj_w, proj_b, ntok);
    }

    // 4. upsweep: out_l += coef * up(out_{l+1}), l = 3..0
    static const float coefs[4] = {1.f, 0.5f, 1.f / 3.f, 0.25f};
    for (int k = 0; k < 4; ++k) {
        int l = 3 - k;
        int H = 128 >> l;
        int ntot = 8 * H * H * 4;
        k_up<<<dim3((ntot + 255) / 256), dim3(256), 0, stream>>>(ws + off_out[l + 1], ws + off_out[l],
                                                                 up_w, H, H, coefs[k], ntot);
    }

    // 5. final transpose to (B, C, W, H)
    k_tr_out<<<dim3(128, 8), dim3(256), 0, stream>>>(ws + off_out[0], out);
}